// Round 6
// baseline (157.385 us; speedup 1.0000x reference)
//
#include <hip/hip_runtime.h>
#include <math.h>

#define NPTS 4096
#define BATCH 4
#define KNB 16
#define BIG 3.0e38f
#define CAP 512    // survivor capacity (expected M ~40-100)

// ---------------------------------------------------------------------------
// Bitonic sort of 64 (d,slot) pairs, one per lane, ascending in d.
// ---------------------------------------------------------------------------
__device__ __forceinline__ void bsort_stage(float& d, int& s, int lane, int k, int j) {
  const float od = __shfl_xor(d, j);
  const int   os = __shfl_xor(s, j);
  const bool keepMin = ((lane & k) == 0) == ((lane & j) == 0);
  const bool takeO = keepMin ? (od < d) : (od > d);
  d = takeO ? od : d;
  s = takeO ? os : s;
}

__device__ __forceinline__ void bitonic_sort64(float& d, int& s, int lane) {
#pragma unroll
  for (int k = 2; k <= 64; k <<= 1) {
#pragma unroll
    for (int j = k >> 1; j >= 1; j >>= 1)
      bsort_stage(d, s, lane, k, j);
  }
}

__device__ __forceinline__ void bitonic_merge64(float& d, int& s, int lane) {
#pragma unroll
  for (int j = 32; j >= 1; j >>= 1)
    bsort_stage(d, s, lane, 64, j);   // k=64: ascending everywhere
}

// ---------------------------------------------------------------------------
// Kernel 1: one block (256 thr) per (point i, batch b, dataset ds).
// Exact 17-NN (incl. self at rank 0): per-thread-min over 16 contiguous
// candidates -> per-wave 17th-order-stat bound via ballot binary search on
// float bits -> tau = min over waves -> collect survivors -> bitonic sort.
// Self (d2 == 0 exactly) sorts to rank 0 and is dropped, matching ref.
// ---------------------------------------------------------------------------
__global__ __launch_bounds__(256)
void knn_kappa_kernel(const float* __restrict__ ori,
                      const float* __restrict__ adv,
                      const float* __restrict__ nrm,
                      float* __restrict__ kappaWs,
                      int* __restrict__ idxWs,
                      float* __restrict__ accum) {
  const int i    = blockIdx.x;
  const int b    = blockIdx.y;
  const int ds   = blockIdx.z;
  const int t    = threadIdx.x;
  const int lane = t & 63;
  const int w    = t >> 6;

  // one block zeroes the kernel-2 accumulators (k2 launches after all k1 blocks)
  if (i == 0 && b == 0 && ds == 0 && t < 8) accum[t] = 0.0f;

  const float* __restrict__ P = (ds == 0 ? ori : adv) + (size_t)b * 3 * NPTS;
  const float4* __restrict__ X4 = (const float4*)(P);
  const float4* __restrict__ Y4 = (const float4*)(P + NPTS);
  const float4* __restrict__ Z4 = (const float4*)(P + 2 * NPTS);

  __shared__ float candD[CAP];
  __shared__ int   candI[CAP];
  __shared__ unsigned int wTau[4];
  __shared__ unsigned int cnt;

  if (t == 0) cnt = 0;

  const float xi = P[i], yi = P[NPTS + i], zi = P[2 * NPTS + i];

  // Distance pass: 16 contiguous candidates per thread via 12 dwordx4 loads.
  float d[16];
  float tmin = BIG;
  const int base4 = t * 4;
#pragma unroll
  for (int k = 0; k < 4; ++k) {
    const float4 xv = X4[base4 + k];
    const float4 yv = Y4[base4 + k];
    const float4 zv = Z4[base4 + k];
    {
      const float dx = xv.x - xi, dy = yv.x - yi, dz = zv.x - zi;
      d[k * 4 + 0] = fmaf(dx, dx, fmaf(dy, dy, dz * dz));
    }
    {
      const float dx = xv.y - xi, dy = yv.y - yi, dz = zv.y - zi;
      d[k * 4 + 1] = fmaf(dx, dx, fmaf(dy, dy, dz * dz));
    }
    {
      const float dx = xv.z - xi, dy = yv.z - yi, dz = zv.z - zi;
      d[k * 4 + 2] = fmaf(dx, dx, fmaf(dy, dy, dz * dz));
    }
    {
      const float dx = xv.w - xi, dy = yv.w - yi, dz = zv.w - zi;
      d[k * 4 + 3] = fmaf(dx, dx, fmaf(dy, dy, dz * dz));
    }
    tmin = fminf(tmin, fminf(fminf(d[k * 4 + 0], d[k * 4 + 1]),
                             fminf(d[k * 4 + 2], d[k * 4 + 3])));
  }

  // Per-wave tau_w >= 17th smallest thread-min (ballot binary search on the
  // top 12 bits of the positive-float bit pattern; uint-monotone).
  {
    const unsigned mb = __float_as_uint(tmin);
    unsigned G = 0;
#pragma unroll
    for (int bit = 11; bit >= 0; --bit) {
      const unsigned trial = G | (1u << bit);
      const unsigned T = (trial << 19) | 0x7FFFFu;
      const int c = __popcll(__ballot(mb <= T));
      if (c < 17) G = trial;        // uniform (ballot result is wave-uniform)
    }
    unsigned T0 = (G << 19) | 0x7FFFFu;
    const int c0 = __popcll(__ballot(mb <= T0));
    if (c0 < 17) T0 = ((G + 1u) << 19) | 0x7FFFFu;
    if (lane == 0) wTau[w] = T0;
  }
  __syncthreads();
  const unsigned tauBits = min(min(wTau[0], wTau[1]), min(wTau[2], wTau[3]));

  // Collect survivors (float-bit compare; self's d2==0 always survives).
#pragma unroll
  for (int u = 0; u < 16; ++u) {
    if (__float_as_uint(d[u]) <= tauBits) {
      const unsigned pos = atomicAdd(&cnt, 1u);
      if (pos < CAP) { candD[pos] = d[u]; candI[pos] = t * 16 + u; }
    }
  }
  __syncthreads();

  // Wave 0: exact sort of the M survivors; ranks 1..16 = the 16 NN.
  if (w == 0) {
    const int M = (int)(cnt < CAP ? cnt : CAP);
    float sd = (lane < M) ? candD[lane] : BIG;
    int   si = (lane < M) ? lane : -1;
    bitonic_sort64(sd, si, lane);
    for (int c0 = 64; c0 < M; c0 += 64) {       // uncommon: M > 64
      const int slot = c0 + lane;
      float vd = (slot < M) ? candD[slot] : BIG;
      int   vi = (slot < M) ? slot : -1;
      bitonic_sort64(vd, vi, lane);
      const float rd = __shfl_xor(vd, 63);      // reverse -> descending
      const int   ri = __shfl_xor(vi, 63);
      if (rd < sd) { sd = rd; si = ri; }        // min-half of bitonic merge
      bitonic_merge64(sd, si, lane);            // re-sort ascending
    }

    // lane r (0..15) takes rank r+1 (rank 0 is self, d2==0).
    const int siN = __shfl(si, lane + 1);
    if (lane < KNB) {
      const int nbj = candI[siN];
      const float vx = P[nbj] - xi;
      const float vy = P[NPTS + nbj] - yi;
      const float vz = P[2 * NPTS + nbj] - zi;
      float L = fmaxf(sqrtf(fmaf(vx, vx, fmaf(vy, vy, vz * vz))), 1e-12f);
      const float* __restrict__ nb_ = nrm + (size_t)b * 3 * NPTS;
      const float nx = nb_[i], ny = nb_[NPTS + i], nz = nb_[2 * NPTS + i];
      float c = fabsf(fmaf(vx, nx, fmaf(vy, ny, vz * nz)) / L);
      c += __shfl_xor(c, 1);
      c += __shfl_xor(c, 2);
      c += __shfl_xor(c, 4);
      c += __shfl_xor(c, 8);
      const size_t row = (size_t)(ds * BATCH + b) * NPTS + i;
      if (lane == 0) kappaWs[row] = c * (1.0f / 16.0f);
      idxWs[row * KNB + lane] = nbj;
    }
  }
}

// ---------------------------------------------------------------------------
// Kernel 2: per (b,i): gather 16 neighbor kappas for both datasets, std with
// ddof=1, d = std_ori - std_adv + 1e-6, reduce d^2; last block finalizes
// out = mean_b sqrt(sum_b) via device-scope atomics.
// ---------------------------------------------------------------------------
__global__ __launch_bounds__(256)
void std_dist_kernel(const float* __restrict__ kappaWs,
                     const int* __restrict__ idxWs,
                     float* __restrict__ accum,
                     float* __restrict__ out) {
  const int i = blockIdx.x * 256 + threadIdx.x;
  const int b = blockIdx.y;

  float s[2];
#pragma unroll
  for (int ds = 0; ds < 2; ++ds) {
    const size_t kb = (size_t)(ds * BATCH + b) * NPTS;
    const int4* __restrict__ ip = (const int4*)(idxWs + (kb + i) * KNB);
    const int4 q0 = ip[0], q1 = ip[1], q2 = ip[2], q3 = ip[3];
    const float* __restrict__ kp = kappaWs + kb;
    float kv[16];
    kv[0] = kp[q0.x];  kv[1] = kp[q0.y];  kv[2] = kp[q0.z];  kv[3] = kp[q0.w];
    kv[4] = kp[q1.x];  kv[5] = kp[q1.y];  kv[6] = kp[q1.z];  kv[7] = kp[q1.w];
    kv[8] = kp[q2.x];  kv[9] = kp[q2.y];  kv[10] = kp[q2.z]; kv[11] = kp[q2.w];
    kv[12] = kp[q3.x]; kv[13] = kp[q3.y]; kv[14] = kp[q3.z]; kv[15] = kp[q3.w];
    float sum = 0.f;
#pragma unroll
    for (int u = 0; u < 16; ++u) sum += kv[u];
    const float mean = sum * (1.0f / 16.0f);
    float ss = 0.f;
#pragma unroll
    for (int u = 0; u < 16; ++u) {
      const float dv = kv[u] - mean;
      ss = fmaf(dv, dv, ss);
    }
    s[ds] = sqrtf(ss * (1.0f / 15.0f));   // unbiased (ddof=1)
  }

  float dq = s[0] - s[1] + 1e-6f;          // PairwiseDistance eps inside norm
  dq = dq * dq;

  dq += __shfl_xor(dq, 32);
  dq += __shfl_xor(dq, 16);
  dq += __shfl_xor(dq, 8);
  dq += __shfl_xor(dq, 4);
  dq += __shfl_xor(dq, 2);
  dq += __shfl_xor(dq, 1);
  __shared__ float red[4];
  if ((threadIdx.x & 63) == 0) red[threadIdx.x >> 6] = dq;
  __syncthreads();

  if (threadIdx.x == 0) {
    const float blockSum = red[0] + red[1] + red[2] + red[3];
    atomicAdd(&accum[b], blockSum);
    __threadfence();
    const unsigned old = atomicAdd((unsigned int*)(accum + 4), 1u);
    if (old == 63) {                        // last of 64 blocks
      float ssum = 0.f;
#pragma unroll
      for (int bb = 0; bb < 4; ++bb) ssum += sqrtf(atomicAdd(&accum[bb], 0.0f));
      out[0] = ssum * 0.25f;
    }
  }
}

extern "C" void kernel_launch(void* const* d_in, const int* in_sizes, int n_in,
                              void* d_out, int out_size, void* d_ws, size_t ws_size,
                              hipStream_t stream) {
  const float* ori = (const float*)d_in[0];
  const float* adv = (const float*)d_in[1];
  const float* nrm = (const float*)d_in[2];
  float* out = (float*)d_out;

  float* kappaWs = (float*)d_ws;                                  // 2*4*4096 f32
  int*   idxWs   = (int*)((char*)d_ws + (size_t)2 * BATCH * NPTS * 4);
  float* accum   = (float*)((char*)d_ws + (size_t)2 * BATCH * NPTS * 4
                                        + (size_t)2 * BATCH * NPTS * KNB * 4);

  dim3 g1(NPTS, BATCH, 2);
  knn_kappa_kernel<<<g1, 256, 0, stream>>>(ori, adv, nrm, kappaWs, idxWs, accum);

  dim3 g2(NPTS / 256, BATCH);
  std_dist_kernel<<<g2, 256, 0, stream>>>(kappaWs, idxWs, accum, out);
}

// Round 8
// 154.324 us; speedup vs baseline: 1.0198x; 1.0198x over previous
//
#include <hip/hip_runtime.h>
#include <math.h>

#define NPTS 4096
#define BATCH 4
#define KNB 16
#define QB 8       // queries per block
#define CAP 256    // survivors per query (measured mean ~60; 8-sigma margin)
#define BIG 3.0e38f

// ---------------------------------------------------------------------------
// Bitonic sort of 64 (d,slot) pairs, one per lane, ascending in d.
// (Proven in rounds 2-6.)
// ---------------------------------------------------------------------------
__device__ __forceinline__ void bsort_stage(float& d, int& s, int lane, int k, int j) {
  const float od = __shfl_xor(d, j);
  const int   os = __shfl_xor(s, j);
  const bool keepMin = ((lane & k) == 0) == ((lane & j) == 0);
  const bool takeO = keepMin ? (od < d) : (od > d);
  d = takeO ? od : d;
  s = takeO ? os : s;
}

__device__ __forceinline__ void bitonic_sort64(float& d, int& s, int lane) {
#pragma unroll
  for (int k = 2; k <= 64; k <<= 1) {
#pragma unroll
    for (int j = k >> 1; j >= 1; j >>= 1)
      bsort_stage(d, s, lane, k, j);
  }
}

__device__ __forceinline__ void bitonic_merge64(float& d, int& s, int lane) {
#pragma unroll
  for (int j = 32; j >= 1; j >>= 1)
    bsort_stage(d, s, lane, 64, j);   // k=64: ascending everywhere
}

// ---------------------------------------------------------------------------
// Kernel 1: one block (256 thr) per 8 consecutive queries of one (b, ds).
// Thread t owns candidates [16t,16t+16), coords cached in registers (loaded
// once, amortized over 8 queries).
// Phase 1 (per query, 1 barrier): distances in regs -> per-wave 17th-order-
// stat bound on thread-mins via 12-bit ballot search (proven r5/r6) -> block
// tau = min over waves -> collect survivors (d,idx) into per-query LDS.
// Phase 2 (barrier-free): wave w sorts queries {2w, 2w+1} with the proven
// bitonic sort; rank 0 is self (d2==0); lanes 0..15 take ranks 1..16,
// compute kappa, write ordered idx. Exactly 16 writes per row always.
// ---------------------------------------------------------------------------
__global__ __launch_bounds__(256)
void knn_kappa_kernel(const float* __restrict__ ori,
                      const float* __restrict__ adv,
                      const float* __restrict__ nrm,
                      float* __restrict__ kappaWs,
                      int* __restrict__ idxWs,
                      float* __restrict__ accum) {
  const int blk  = blockIdx.x;
  const int b    = blockIdx.y;
  const int ds   = blockIdx.z;
  const int t    = threadIdx.x;
  const int lane = t & 63;
  const int w    = t >> 6;
  const int i0   = blk * QB;

  if (blk == 0 && b == 0 && ds == 0 && t < 8) accum[t] = 0.0f;

  const float* __restrict__ P = (ds == 0 ? ori : adv) + (size_t)b * 3 * NPTS;

  __shared__ float qx[QB], qy[QB], qz[QB];
  __shared__ unsigned wTau[QB][4];
  __shared__ unsigned cnt[QB];
  __shared__ float candD[QB][CAP];
  __shared__ int   candI[QB][CAP];

  if (t < QB) {
    cnt[t] = 0;
    qx[t] = P[i0 + t];
    qy[t] = P[NPTS + i0 + t];
    qz[t] = P[2 * NPTS + i0 + t];
  }

  // Candidate coords into registers: 12 dwordx4 loads, once per block.
  const float4* __restrict__ X4 = (const float4*)(P);
  const float4* __restrict__ Y4 = (const float4*)(P + NPTS);
  const float4* __restrict__ Z4 = (const float4*)(P + 2 * NPTS);
  float cx[16], cy[16], cz[16];
#pragma unroll
  for (int k = 0; k < 4; ++k) {
    const float4 xv = X4[t * 4 + k];
    const float4 yv = Y4[t * 4 + k];
    const float4 zv = Z4[t * 4 + k];
    cx[k*4+0]=xv.x; cx[k*4+1]=xv.y; cx[k*4+2]=xv.z; cx[k*4+3]=xv.w;
    cy[k*4+0]=yv.x; cy[k*4+1]=yv.y; cy[k*4+2]=yv.z; cy[k*4+3]=yv.w;
    cz[k*4+0]=zv.x; cz[k*4+1]=zv.y; cz[k*4+2]=zv.z; cz[k*4+3]=zv.w;
  }
  __syncthreads();

  // ---- Phase 1: per query distances + tau + collect ----
  for (int q = 0; q < QB; ++q) {
    const float xi = qx[q], yi = qy[q], zi = qz[q];
    float d[16];
    float tmin = BIG;
#pragma unroll
    for (int u = 0; u < 16; ++u) {
      const float dx = cx[u] - xi;
      const float dy = cy[u] - yi;
      const float dz = cz[u] - zi;
      d[u] = fmaf(dx, dx, fmaf(dy, dy, dz * dz));
      tmin = fminf(tmin, d[u]);     // self d2 == 0 exactly; stays included
    }

    // Per-wave bound >= 17th smallest candidate (via thread-min order stat;
    // 12-bit prefix of f32 bits, uint-monotone). Proven r5/r6.
    {
      const unsigned mb = __float_as_uint(tmin);
      unsigned G = 0;
#pragma unroll
      for (int bit = 11; bit >= 0; --bit) {
        const unsigned trial = G | (1u << bit);
        const unsigned T = (trial << 19) | 0x7FFFFu;
        const int c = __popcll(__ballot(mb <= T));
        if (c < 17) G = trial;
      }
      unsigned T0 = (G << 19) | 0x7FFFFu;
      const int c0 = __popcll(__ballot(mb <= T0));
      if (c0 < 17) T0 = ((G + 1u) << 19) | 0x7FFFFu;
      if (lane == 0) wTau[q][w] = T0;
    }
    __syncthreads();
    const unsigned tb = min(min(wTau[q][0], wTau[q][1]),
                            min(wTau[q][2], wTau[q][3]));

    // Collect survivors (incl self). Guaranteed superset of the true top-17.
#pragma unroll
    for (int u = 0; u < 16; ++u) {
      if (__float_as_uint(d[u]) <= tb) {
        const unsigned pos = atomicAdd(&cnt[q], 1u);
        if (pos < CAP) {
          candD[q][pos] = d[u];
          candI[q][pos] = t * 16 + u;
        }
      }
    }
    // no trailing barrier: buffers q are only read after the phase-1 loop
  }
  __syncthreads();

  // ---- Phase 2: wave w resolves queries 2w and 2w+1 (no barriers) ----
#pragma unroll
  for (int s = 0; s < 2; ++s) {
    const int q  = w * 2 + s;
    const int qi = i0 + q;
    const int M  = (int)(cnt[q] < CAP ? cnt[q] : CAP);

    float sd = (lane < M) ? candD[q][lane] : BIG;
    int   si = (lane < M) ? lane : -1;
    bitonic_sort64(sd, si, lane);
    for (int c0 = 64; c0 < M; c0 += 64) {       // uncommon: M > 64
      const int slot = c0 + lane;
      float vd = (slot < M) ? candD[q][slot] : BIG;
      int   vi = (slot < M) ? slot : -1;
      bitonic_sort64(vd, vi, lane);
      const float rd = __shfl_xor(vd, 63);      // reverse -> descending
      const int   ri = __shfl_xor(vi, 63);
      if (rd < sd) { sd = rd; si = ri; }        // min-half of bitonic merge
      bitonic_merge64(sd, si, lane);            // re-sort ascending
    }

    // lane r (0..15) takes rank r+1 (rank 0 is self, d2==0).
    const int siN = __shfl(si, lane + 1);
    if (lane < KNB) {
      const int nbj = candI[q][siN];
      const float xi = qx[q], yi = qy[q], zi = qz[q];
      const float vx = P[nbj] - xi;
      const float vy = P[NPTS + nbj] - yi;
      const float vz = P[2 * NPTS + nbj] - zi;
      const float L = fmaxf(sqrtf(fmaf(vx, vx, fmaf(vy, vy, vz * vz))), 1e-12f);
      const float* __restrict__ nb_ = nrm + (size_t)b * 3 * NPTS;
      const float nx = nb_[qi], ny = nb_[NPTS + qi], nz = nb_[2 * NPTS + qi];
      float c = fabsf(fmaf(vx, nx, fmaf(vy, ny, vz * nz)) / L);
      c += __shfl_xor(c, 1);
      c += __shfl_xor(c, 2);
      c += __shfl_xor(c, 4);
      c += __shfl_xor(c, 8);
      const size_t row = (size_t)(ds * BATCH + b) * NPTS + qi;
      if (lane == 0) kappaWs[row] = c * (1.0f / 16.0f);
      idxWs[row * KNB + lane] = nbj;
    }
  }
}

// ---------------------------------------------------------------------------
// Kernel 2 (verbatim round 6, proven): per (b,i) gather 16 neighbor kappas
// for both datasets, ddof=1 std, d = std_ori - std_adv + 1e-6, reduce d^2;
// last block finalizes out = mean_b sqrt(sum_b) via device-scope atomics.
// ---------------------------------------------------------------------------
__global__ __launch_bounds__(256)
void std_dist_kernel(const float* __restrict__ kappaWs,
                     const int* __restrict__ idxWs,
                     float* __restrict__ accum,
                     float* __restrict__ out) {
  const int i = blockIdx.x * 256 + threadIdx.x;
  const int b = blockIdx.y;

  float s[2];
#pragma unroll
  for (int ds = 0; ds < 2; ++ds) {
    const size_t kb = (size_t)(ds * BATCH + b) * NPTS;
    const int4* __restrict__ ip = (const int4*)(idxWs + (kb + i) * KNB);
    const int4 q0 = ip[0], q1 = ip[1], q2 = ip[2], q3 = ip[3];
    const float* __restrict__ kp = kappaWs + kb;
    float kv[16];
    kv[0] = kp[q0.x];  kv[1] = kp[q0.y];  kv[2] = kp[q0.z];  kv[3] = kp[q0.w];
    kv[4] = kp[q1.x];  kv[5] = kp[q1.y];  kv[6] = kp[q1.z];  kv[7] = kp[q1.w];
    kv[8] = kp[q2.x];  kv[9] = kp[q2.y];  kv[10] = kp[q2.z]; kv[11] = kp[q2.w];
    kv[12] = kp[q3.x]; kv[13] = kp[q3.y]; kv[14] = kp[q3.z]; kv[15] = kp[q3.w];
    float sum = 0.f;
#pragma unroll
    for (int u = 0; u < 16; ++u) sum += kv[u];
    const float mean = sum * (1.0f / 16.0f);
    float ss = 0.f;
#pragma unroll
    for (int u = 0; u < 16; ++u) {
      const float dv = kv[u] - mean;
      ss = fmaf(dv, dv, ss);
    }
    s[ds] = sqrtf(ss * (1.0f / 15.0f));   // unbiased (ddof=1)
  }

  float dq = s[0] - s[1] + 1e-6f;          // PairwiseDistance eps inside norm
  dq = dq * dq;

  dq += __shfl_xor(dq, 32);
  dq += __shfl_xor(dq, 16);
  dq += __shfl_xor(dq, 8);
  dq += __shfl_xor(dq, 4);
  dq += __shfl_xor(dq, 2);
  dq += __shfl_xor(dq, 1);
  __shared__ float red[4];
  if ((threadIdx.x & 63) == 0) red[threadIdx.x >> 6] = dq;
  __syncthreads();

  if (threadIdx.x == 0) {
    const float blockSum = red[0] + red[1] + red[2] + red[3];
    atomicAdd(&accum[b], blockSum);
    __threadfence();
    const unsigned old = atomicAdd((unsigned int*)(accum + 4), 1u);
    if (old == 63) {                        // last of 64 blocks
      float ssum = 0.f;
#pragma unroll
      for (int bb = 0; bb < 4; ++bb) ssum += sqrtf(atomicAdd(&accum[bb], 0.0f));
      out[0] = ssum * 0.25f;
    }
  }
}

extern "C" void kernel_launch(void* const* d_in, const int* in_sizes, int n_in,
                              void* d_out, int out_size, void* d_ws, size_t ws_size,
                              hipStream_t stream) {
  const float* ori = (const float*)d_in[0];
  const float* adv = (const float*)d_in[1];
  const float* nrm = (const float*)d_in[2];
  float* out = (float*)d_out;

  float* kappaWs = (float*)d_ws;                                  // 2*4*4096 f32
  int*   idxWs   = (int*)((char*)d_ws + (size_t)2 * BATCH * NPTS * 4);
  float* accum   = (float*)((char*)d_ws + (size_t)2 * BATCH * NPTS * 4
                                        + (size_t)2 * BATCH * NPTS * KNB * 4);

  dim3 g1(NPTS / QB, BATCH, 2);
  knn_kappa_kernel<<<g1, 256, 0, stream>>>(ori, adv, nrm, kappaWs, idxWs, accum);

  dim3 g2(NPTS / 256, BATCH);
  std_dist_kernel<<<g2, 256, 0, stream>>>(kappaWs, idxWs, accum, out);
}

// Round 9
// 152.202 us; speedup vs baseline: 1.0341x; 1.0139x over previous
//
#include <hip/hip_runtime.h>
#include <math.h>

#define NPTS 4096
#define BATCH 4
#define KNB 16
#define QB 8       // queries per block
#define CAP 256    // survivors per query (est mean ~95, +14 sigma margin)
#define BIG 3.0e38f

// ---------------------------------------------------------------------------
// Kernel 1: one block (256 thr) per 8 consecutive queries of one (b, ds).
// Thread t owns candidates [16t,16t+16), coords cached in registers.
// Phase 1 (barrier-free): per query, distances in regs -> PER-WAVE
// 17th-order-stat bound on thread-mins (12-bit ballot search, proven r5-r8;
// exact since tau_w >= d17(wave subset) >= d17(global)) -> collect survivors
// (float-bit key, cand idx) into per-query LDS. ONE barrier at the end.
// Phase 2 (barrier-free): wave w resolves queries {w, w+4}: exact 17th-
// smallest key K17 via 31-round MSB radix ballot search (handles duplicate
// keys); select {k < K17, not self} + first (17 - count_less) ties.
// Always exactly 16 neighbors. Unordered (std/mean are permutation-inv).
// ---------------------------------------------------------------------------
__global__ __launch_bounds__(256)
void knn_kappa_kernel(const float* __restrict__ ori,
                      const float* __restrict__ adv,
                      const float* __restrict__ nrm,
                      float* __restrict__ kappaWs,
                      int* __restrict__ idxWs,
                      float* __restrict__ accum) {
  const int blk  = blockIdx.x;
  const int b    = blockIdx.y;
  const int ds   = blockIdx.z;
  const int t    = threadIdx.x;
  const int lane = t & 63;
  const int w    = t >> 6;
  const int i0   = blk * QB;

  if (blk == 0 && b == 0 && ds == 0 && t < 8) accum[t] = 0.0f;

  const float* __restrict__ P = (ds == 0 ? ori : adv) + (size_t)b * 3 * NPTS;

  __shared__ unsigned cnt[QB];
  __shared__ unsigned sKey[QB][CAP];
  __shared__ int      sIdx[QB][CAP];

  if (t < QB) cnt[t] = 0;

  // Candidate coords into registers: 12 dwordx4 loads, once per block.
  const float4* __restrict__ X4 = (const float4*)(P);
  const float4* __restrict__ Y4 = (const float4*)(P + NPTS);
  const float4* __restrict__ Z4 = (const float4*)(P + 2 * NPTS);
  float cx[16], cy[16], cz[16];
#pragma unroll
  for (int k = 0; k < 4; ++k) {
    const float4 xv = X4[t * 4 + k];
    const float4 yv = Y4[t * 4 + k];
    const float4 zv = Z4[t * 4 + k];
    cx[k*4+0]=xv.x; cx[k*4+1]=xv.y; cx[k*4+2]=xv.z; cx[k*4+3]=xv.w;
    cy[k*4+0]=yv.x; cy[k*4+1]=yv.y; cy[k*4+2]=yv.z; cy[k*4+3]=yv.w;
    cz[k*4+0]=zv.x; cz[k*4+1]=zv.y; cz[k*4+2]=zv.z; cz[k*4+3]=zv.w;
  }
  __syncthreads();   // cnt zeros visible; nothing else shared yet

  // ---- Phase 1: per query distances + per-wave tau + collect (no barriers)
  for (int q = 0; q < QB; ++q) {
    const int qi = i0 + q;
    const float xi = P[qi], yi = P[NPTS + qi], zi = P[2 * NPTS + qi];
    float d[16];
    float tmin = BIG;
#pragma unroll
    for (int u = 0; u < 16; ++u) {
      const float dx = cx[u] - xi;
      const float dy = cy[u] - yi;
      const float dz = cz[u] - zi;
      d[u] = fmaf(dx, dx, fmaf(dy, dy, dz * dz));   // self: exactly 0
      tmin = fminf(tmin, d[u]);
    }

    // Per-wave bound >= 17th smallest thread-min (12-bit prefix of f32 bits).
    unsigned tb;
    {
      const unsigned mb = __float_as_uint(tmin);
      unsigned G = 0;
#pragma unroll
      for (int bit = 11; bit >= 0; --bit) {
        const unsigned trial = G | (1u << bit);
        const unsigned T = (trial << 19) | 0x7FFFFu;
        const int c = __popcll(__ballot(mb <= T));
        if (c < 17) G = trial;
      }
      unsigned T0 = (G << 19) | 0x7FFFFu;
      const int c0 = __popcll(__ballot(mb <= T0));
      if (c0 < 17) T0 = ((G + 1u) << 19) | 0x7FFFFu;
      tb = T0;
    }

    // Collect survivors (incl self). Superset of true top-17 guaranteed.
#pragma unroll
    for (int u = 0; u < 16; ++u) {
      const unsigned kb = __float_as_uint(d[u]);
      if (kb <= tb) {
        const unsigned pos = atomicAdd(&cnt[q], 1u);
        if (pos < CAP) {
          sKey[q][pos] = kb;
          sIdx[q][pos] = t * 16 + u;
        }
      }
    }
  }
  __syncthreads();   // all collects visible

  // ---- Phase 2: wave w resolves queries w and w+4 (no barriers) ----
#pragma unroll
  for (int s = 0; s < 2; ++s) {
    const int q  = w + 4 * s;
    const int qi = i0 + q;
    const int M  = (int)(cnt[q] < CAP ? cnt[q] : CAP);

    unsigned k0, k1, k2, k3;
    int id0, id1, id2, id3;
    {
      const int s0 = lane, s1 = lane + 64, s2 = lane + 128, s3 = lane + 192;
      k0 = (s0 < M) ? sKey[q][s0] : 0xFFFFFFFFu;  id0 = (s0 < M) ? sIdx[q][s0] : -1;
      k1 = (s1 < M) ? sKey[q][s1] : 0xFFFFFFFFu;  id1 = (s1 < M) ? sIdx[q][s1] : -1;
      k2 = (s2 < M) ? sKey[q][s2] : 0xFFFFFFFFu;  id2 = (s2 < M) ? sIdx[q][s2] : -1;
      k3 = (s3 < M) ? sKey[q][s3] : 0xFFFFFFFFu;  id3 = (s3 < M) ? sIdx[q][s3] : -1;
    }

    // Exact 17th smallest key (incl duplicates): MSB-first radix search.
    unsigned pfx = 0;
#pragma unroll
    for (int bit = 30; bit >= 0; --bit) {
      const unsigned T = pfx | ((1u << bit) - 1u);
      const int cb = __popcll(__ballot(k0 <= T)) + __popcll(__ballot(k1 <= T))
                   + __popcll(__ballot(k2 <= T)) + __popcll(__ballot(k3 <= T));
      if (cb < 17) pfx |= (1u << bit);
    }
    const unsigned K17 = pfx;   // count(< K17) < 17 <= count(<= K17)

    const unsigned long long blt = (1ull << lane) - 1ull;
    const unsigned long long bt0 = __ballot(k0 == K17);
    const unsigned long long bt1 = __ballot(k1 == K17);
    const unsigned long long bt2 = __ballot(k2 == K17);
    const unsigned long long bt3 = __ballot(k3 == K17);
    const int cless = __popcll(__ballot(k0 < K17)) + __popcll(__ballot(k1 < K17))
                    + __popcll(__ballot(k2 < K17)) + __popcll(__ballot(k3 < K17));
    const int need = 17 - cless;     // >=1; tie multiplicity >= need guaranteed

    const int p0 = __popcll(bt0), p1 = __popcll(bt1), p2 = __popcll(bt2);
    const int tr0 = __popcll(bt0 & blt);
    const int tr1 = p0 + __popcll(bt1 & blt);
    const int tr2 = p0 + p1 + __popcll(bt2 & blt);
    const int tr3 = p0 + p1 + p2 + __popcll(bt3 & blt);

    // neighbor selection: {k < K17, not self} U first-need ties (self: key 0)
    const bool n0 = (k0 < K17 && id0 != qi) || (k0 == K17 && tr0 < need);
    const bool n1 = (k1 < K17 && id1 != qi) || (k1 == K17 && tr1 < need);
    const bool n2 = (k2 < K17 && id2 != qi) || (k2 == K17 && tr2 < need);
    const bool n3 = (k3 < K17 && id3 != qi) || (k3 == K17 && tr3 < need);
    const unsigned long long m0 = __ballot(n0);
    const unsigned long long m1 = __ballot(n1);
    const unsigned long long m2 = __ballot(n2);
    const unsigned long long m3 = __ballot(n3);
    const int q0c = __popcll(m0), q1c = __popcll(m1), q2c = __popcll(m2);
    const int r0 = __popcll(m0 & blt);
    const int r1 = q0c + __popcll(m1 & blt);
    const int r2 = q0c + q1c + __popcll(m2 & blt);
    const int r3 = q0c + q1c + q2c + __popcll(m3 & blt);

    const float xi = P[qi], yi = P[NPTS + qi], zi = P[2 * NPTS + qi];
    const float* __restrict__ nb_ = nrm + (size_t)b * 3 * NPTS;
    const float nx = nb_[qi], ny = nb_[NPTS + qi], nz = nb_[2 * NPTS + qi];
    const size_t row = (size_t)(ds * BATCH + b) * NPTS + qi;

    float csum = 0.f;
    if (n0) {
      const float vx = P[id0] - xi, vy = P[NPTS + id0] - yi, vz = P[2*NPTS + id0] - zi;
      const float vv = fmaf(vx, vx, fmaf(vy, vy, vz * vz));
      csum += fabsf(fmaf(vx, nx, fmaf(vy, ny, vz * nz))) * rsqrtf(vv);
      idxWs[row * KNB + r0] = id0;
    }
    if (n1) {
      const float vx = P[id1] - xi, vy = P[NPTS + id1] - yi, vz = P[2*NPTS + id1] - zi;
      const float vv = fmaf(vx, vx, fmaf(vy, vy, vz * vz));
      csum += fabsf(fmaf(vx, nx, fmaf(vy, ny, vz * nz))) * rsqrtf(vv);
      idxWs[row * KNB + r1] = id1;
    }
    if (n2) {
      const float vx = P[id2] - xi, vy = P[NPTS + id2] - yi, vz = P[2*NPTS + id2] - zi;
      const float vv = fmaf(vx, vx, fmaf(vy, vy, vz * vz));
      csum += fabsf(fmaf(vx, nx, fmaf(vy, ny, vz * nz))) * rsqrtf(vv);
      idxWs[row * KNB + r2] = id2;
    }
    if (n3) {
      const float vx = P[id3] - xi, vy = P[NPTS + id3] - yi, vz = P[2*NPTS + id3] - zi;
      const float vv = fmaf(vx, vx, fmaf(vy, vy, vz * vz));
      csum += fabsf(fmaf(vx, nx, fmaf(vy, ny, vz * nz))) * rsqrtf(vv);
      idxWs[row * KNB + r3] = id3;
    }

    csum += __shfl_xor(csum, 1);
    csum += __shfl_xor(csum, 2);
    csum += __shfl_xor(csum, 4);
    csum += __shfl_xor(csum, 8);
    csum += __shfl_xor(csum, 16);
    csum += __shfl_xor(csum, 32);
    if (lane == 0) kappaWs[row] = csum * (1.0f / 16.0f);
  }
}

// ---------------------------------------------------------------------------
// Kernel 2 (verbatim r6/r8, proven): per (b,i) gather 16 neighbor kappas for
// both datasets, ddof=1 std, d = std_ori - std_adv + 1e-6, reduce d^2; last
// block finalizes out = mean_b sqrt(sum_b) via device-scope atomics.
// ---------------------------------------------------------------------------
__global__ __launch_bounds__(256)
void std_dist_kernel(const float* __restrict__ kappaWs,
                     const int* __restrict__ idxWs,
                     float* __restrict__ accum,
                     float* __restrict__ out) {
  const int i = blockIdx.x * 256 + threadIdx.x;
  const int b = blockIdx.y;

  float s[2];
#pragma unroll
  for (int ds = 0; ds < 2; ++ds) {
    const size_t kb = (size_t)(ds * BATCH + b) * NPTS;
    const int4* __restrict__ ip = (const int4*)(idxWs + (kb + i) * KNB);
    const int4 q0 = ip[0], q1 = ip[1], q2 = ip[2], q3 = ip[3];
    const float* __restrict__ kp = kappaWs + kb;
    float kv[16];
    kv[0] = kp[q0.x];  kv[1] = kp[q0.y];  kv[2] = kp[q0.z];  kv[3] = kp[q0.w];
    kv[4] = kp[q1.x];  kv[5] = kp[q1.y];  kv[6] = kp[q1.z];  kv[7] = kp[q1.w];
    kv[8] = kp[q2.x];  kv[9] = kp[q2.y];  kv[10] = kp[q2.z]; kv[11] = kp[q2.w];
    kv[12] = kp[q3.x]; kv[13] = kp[q3.y]; kv[14] = kp[q3.z]; kv[15] = kp[q3.w];
    float sum = 0.f;
#pragma unroll
    for (int u = 0; u < 16; ++u) sum += kv[u];
    const float mean = sum * (1.0f / 16.0f);
    float ss = 0.f;
#pragma unroll
    for (int u = 0; u < 16; ++u) {
      const float dv = kv[u] - mean;
      ss = fmaf(dv, dv, ss);
    }
    s[ds] = sqrtf(ss * (1.0f / 15.0f));   // unbiased (ddof=1)
  }

  float dq = s[0] - s[1] + 1e-6f;          // PairwiseDistance eps inside norm
  dq = dq * dq;

  dq += __shfl_xor(dq, 32);
  dq += __shfl_xor(dq, 16);
  dq += __shfl_xor(dq, 8);
  dq += __shfl_xor(dq, 4);
  dq += __shfl_xor(dq, 2);
  dq += __shfl_xor(dq, 1);
  __shared__ float red[4];
  if ((threadIdx.x & 63) == 0) red[threadIdx.x >> 6] = dq;
  __syncthreads();

  if (threadIdx.x == 0) {
    const float blockSum = red[0] + red[1] + red[2] + red[3];
    atomicAdd(&accum[b], blockSum);
    __threadfence();
    const unsigned old = atomicAdd((unsigned int*)(accum + 4), 1u);
    if (old == 63) {                        // last of 64 blocks
      float ssum = 0.f;
#pragma unroll
      for (int bb = 0; bb < 4; ++bb) ssum += sqrtf(atomicAdd(&accum[bb], 0.0f));
      out[0] = ssum * 0.25f;
    }
  }
}

extern "C" void kernel_launch(void* const* d_in, const int* in_sizes, int n_in,
                              void* d_out, int out_size, void* d_ws, size_t ws_size,
                              hipStream_t stream) {
  const float* ori = (const float*)d_in[0];
  const float* adv = (const float*)d_in[1];
  const float* nrm = (const float*)d_in[2];
  float* out = (float*)d_out;

  float* kappaWs = (float*)d_ws;                                  // 2*4*4096 f32
  int*   idxWs   = (int*)((char*)d_ws + (size_t)2 * BATCH * NPTS * 4);
  float* accum   = (float*)((char*)d_ws + (size_t)2 * BATCH * NPTS * 4
                                        + (size_t)2 * BATCH * NPTS * KNB * 4);

  dim3 g1(NPTS / QB, BATCH, 2);
  knn_kappa_kernel<<<g1, 256, 0, stream>>>(ori, adv, nrm, kappaWs, idxWs, accum);

  dim3 g2(NPTS / 256, BATCH);
  std_dist_kernel<<<g2, 256, 0, stream>>>(kappaWs, idxWs, accum, out);
}

// Round 10
// 151.166 us; speedup vs baseline: 1.0411x; 1.0069x over previous
//
#include <hip/hip_runtime.h>
#include <math.h>

#define NPTS 4096
#define BATCH 4
#define KNB 16
#define QB 8       // queries per block
#define CAP 256    // survivors per query (est mean ~95, +14 sigma margin)
#define BIG 3.0e38f

// ---------------------------------------------------------------------------
// Kernel 1: one block (256 thr) per 8 consecutive queries of one (b, ds).
// Thread t owns candidates [16t,16t+16), coords cached in registers.
// __launch_bounds__(256, 1): release the VGPR cap — without it the compiler
// allocated 40 VGPRs and spilled cx/cy/cz[16]+d[16] to scratch (r9 counters:
// WRITE_SIZE 2.2 GB / FETCH_SIZE 2.0 GB per dispatch = spill round-trip).
// Phase 1 (barrier-free): per query, distances in regs -> PER-WAVE
// 17th-order-stat bound on thread-mins (12-bit ballot search; exact since
// tau_w >= d17(wave subset) >= d17(global)) -> collect survivors into LDS.
// Phase 2 (barrier-free): wave w resolves queries {w, w+4}: exact 17th-
// smallest key via 31-round MSB radix ballot search (duplicate-safe);
// select {k < K17, not self} + first (17 - count_less) ties.
// Always exactly 16 neighbors. Unordered (std/mean are permutation-inv).
// ---------------------------------------------------------------------------
__global__ __launch_bounds__(256, 1)
void knn_kappa_kernel(const float* __restrict__ ori,
                      const float* __restrict__ adv,
                      const float* __restrict__ nrm,
                      float* __restrict__ kappaWs,
                      int* __restrict__ idxWs,
                      float* __restrict__ accum) {
  const int blk  = blockIdx.x;
  const int b    = blockIdx.y;
  const int ds   = blockIdx.z;
  const int t    = threadIdx.x;
  const int lane = t & 63;
  const int w    = t >> 6;
  const int i0   = blk * QB;

  if (blk == 0 && b == 0 && ds == 0 && t < 8) accum[t] = 0.0f;

  const float* __restrict__ P = (ds == 0 ? ori : adv) + (size_t)b * 3 * NPTS;

  __shared__ unsigned cnt[QB];
  __shared__ unsigned sKey[QB][CAP];
  __shared__ int      sIdx[QB][CAP];

  if (t < QB) cnt[t] = 0;

  // Candidate coords into registers: 12 dwordx4 loads, once per block.
  const float4* __restrict__ X4 = (const float4*)(P);
  const float4* __restrict__ Y4 = (const float4*)(P + NPTS);
  const float4* __restrict__ Z4 = (const float4*)(P + 2 * NPTS);
  float cx[16], cy[16], cz[16];
#pragma unroll
  for (int k = 0; k < 4; ++k) {
    const float4 xv = X4[t * 4 + k];
    const float4 yv = Y4[t * 4 + k];
    const float4 zv = Z4[t * 4 + k];
    cx[k*4+0]=xv.x; cx[k*4+1]=xv.y; cx[k*4+2]=xv.z; cx[k*4+3]=xv.w;
    cy[k*4+0]=yv.x; cy[k*4+1]=yv.y; cy[k*4+2]=yv.z; cy[k*4+3]=yv.w;
    cz[k*4+0]=zv.x; cz[k*4+1]=zv.y; cz[k*4+2]=zv.z; cz[k*4+3]=zv.w;
  }
  __syncthreads();   // cnt zeros visible; nothing else shared yet

  // ---- Phase 1: per query distances + per-wave tau + collect (no barriers)
  for (int q = 0; q < QB; ++q) {
    const int qi = i0 + q;
    const float xi = P[qi], yi = P[NPTS + qi], zi = P[2 * NPTS + qi];
    float d[16];
    float tmin = BIG;
#pragma unroll
    for (int u = 0; u < 16; ++u) {
      const float dx = cx[u] - xi;
      const float dy = cy[u] - yi;
      const float dz = cz[u] - zi;
      d[u] = fmaf(dx, dx, fmaf(dy, dy, dz * dz));   // self: exactly 0
      tmin = fminf(tmin, d[u]);
    }

    // Per-wave bound >= 17th smallest thread-min (12-bit prefix of f32 bits).
    unsigned tb;
    {
      const unsigned mb = __float_as_uint(tmin);
      unsigned G = 0;
#pragma unroll
      for (int bit = 11; bit >= 0; --bit) {
        const unsigned trial = G | (1u << bit);
        const unsigned T = (trial << 19) | 0x7FFFFu;
        const int c = __popcll(__ballot(mb <= T));
        if (c < 17) G = trial;
      }
      unsigned T0 = (G << 19) | 0x7FFFFu;
      const int c0 = __popcll(__ballot(mb <= T0));
      if (c0 < 17) T0 = ((G + 1u) << 19) | 0x7FFFFu;
      tb = T0;
    }

    // Collect survivors (incl self). Superset of true top-17 guaranteed.
#pragma unroll
    for (int u = 0; u < 16; ++u) {
      const unsigned kb = __float_as_uint(d[u]);
      if (kb <= tb) {
        const unsigned pos = atomicAdd(&cnt[q], 1u);
        if (pos < CAP) {
          sKey[q][pos] = kb;
          sIdx[q][pos] = t * 16 + u;
        }
      }
    }
  }
  __syncthreads();   // all collects visible

  // ---- Phase 2: wave w resolves queries w and w+4 (no barriers) ----
#pragma unroll
  for (int s = 0; s < 2; ++s) {
    const int q  = w + 4 * s;
    const int qi = i0 + q;
    const int M  = (int)(cnt[q] < CAP ? cnt[q] : CAP);

    unsigned k0, k1, k2, k3;
    int id0, id1, id2, id3;
    {
      const int s0 = lane, s1 = lane + 64, s2 = lane + 128, s3 = lane + 192;
      k0 = (s0 < M) ? sKey[q][s0] : 0xFFFFFFFFu;  id0 = (s0 < M) ? sIdx[q][s0] : -1;
      k1 = (s1 < M) ? sKey[q][s1] : 0xFFFFFFFFu;  id1 = (s1 < M) ? sIdx[q][s1] : -1;
      k2 = (s2 < M) ? sKey[q][s2] : 0xFFFFFFFFu;  id2 = (s2 < M) ? sIdx[q][s2] : -1;
      k3 = (s3 < M) ? sKey[q][s3] : 0xFFFFFFFFu;  id3 = (s3 < M) ? sIdx[q][s3] : -1;
    }

    // Exact 17th smallest key (incl duplicates): MSB-first radix search.
    unsigned pfx = 0;
#pragma unroll
    for (int bit = 30; bit >= 0; --bit) {
      const unsigned T = pfx | ((1u << bit) - 1u);
      const int cb = __popcll(__ballot(k0 <= T)) + __popcll(__ballot(k1 <= T))
                   + __popcll(__ballot(k2 <= T)) + __popcll(__ballot(k3 <= T));
      if (cb < 17) pfx |= (1u << bit);
    }
    const unsigned K17 = pfx;   // count(< K17) < 17 <= count(<= K17)

    const unsigned long long blt = (1ull << lane) - 1ull;
    const unsigned long long bt0 = __ballot(k0 == K17);
    const unsigned long long bt1 = __ballot(k1 == K17);
    const unsigned long long bt2 = __ballot(k2 == K17);
    const unsigned long long bt3 = __ballot(k3 == K17);
    const int cless = __popcll(__ballot(k0 < K17)) + __popcll(__ballot(k1 < K17))
                    + __popcll(__ballot(k2 < K17)) + __popcll(__ballot(k3 < K17));
    const int need = 17 - cless;     // >=1; tie multiplicity >= need guaranteed

    const int p0 = __popcll(bt0), p1 = __popcll(bt1), p2 = __popcll(bt2);
    const int tr0 = __popcll(bt0 & blt);
    const int tr1 = p0 + __popcll(bt1 & blt);
    const int tr2 = p0 + p1 + __popcll(bt2 & blt);
    const int tr3 = p0 + p1 + p2 + __popcll(bt3 & blt);

    // neighbor selection: {k < K17, not self} U first-need ties (self: key 0)
    const bool n0 = (k0 < K17 && id0 != qi) || (k0 == K17 && tr0 < need);
    const bool n1 = (k1 < K17 && id1 != qi) || (k1 == K17 && tr1 < need);
    const bool n2 = (k2 < K17 && id2 != qi) || (k2 == K17 && tr2 < need);
    const bool n3 = (k3 < K17 && id3 != qi) || (k3 == K17 && tr3 < need);
    const unsigned long long m0 = __ballot(n0);
    const unsigned long long m1 = __ballot(n1);
    const unsigned long long m2 = __ballot(n2);
    const unsigned long long m3 = __ballot(n3);
    const int q0c = __popcll(m0), q1c = __popcll(m1), q2c = __popcll(m2);
    const int r0 = __popcll(m0 & blt);
    const int r1 = q0c + __popcll(m1 & blt);
    const int r2 = q0c + q1c + __popcll(m2 & blt);
    const int r3 = q0c + q1c + q2c + __popcll(m3 & blt);

    const float xi = P[qi], yi = P[NPTS + qi], zi = P[2 * NPTS + qi];
    const float* __restrict__ nb_ = nrm + (size_t)b * 3 * NPTS;
    const float nx = nb_[qi], ny = nb_[NPTS + qi], nz = nb_[2 * NPTS + qi];
    const size_t row = (size_t)(ds * BATCH + b) * NPTS + qi;

    float csum = 0.f;
    if (n0) {
      const float vx = P[id0] - xi, vy = P[NPTS + id0] - yi, vz = P[2*NPTS + id0] - zi;
      const float vv = fmaf(vx, vx, fmaf(vy, vy, vz * vz));
      csum += fabsf(fmaf(vx, nx, fmaf(vy, ny, vz * nz))) * rsqrtf(vv);
      idxWs[row * KNB + r0] = id0;
    }
    if (n1) {
      const float vx = P[id1] - xi, vy = P[NPTS + id1] - yi, vz = P[2*NPTS + id1] - zi;
      const float vv = fmaf(vx, vx, fmaf(vy, vy, vz * vz));
      csum += fabsf(fmaf(vx, nx, fmaf(vy, ny, vz * nz))) * rsqrtf(vv);
      idxWs[row * KNB + r1] = id1;
    }
    if (n2) {
      const float vx = P[id2] - xi, vy = P[NPTS + id2] - yi, vz = P[2*NPTS + id2] - zi;
      const float vv = fmaf(vx, vx, fmaf(vy, vy, vz * vz));
      csum += fabsf(fmaf(vx, nx, fmaf(vy, ny, vz * nz))) * rsqrtf(vv);
      idxWs[row * KNB + r2] = id2;
    }
    if (n3) {
      const float vx = P[id3] - xi, vy = P[NPTS + id3] - yi, vz = P[2*NPTS + id3] - zi;
      const float vv = fmaf(vx, vx, fmaf(vy, vy, vz * vz));
      csum += fabsf(fmaf(vx, nx, fmaf(vy, ny, vz * nz))) * rsqrtf(vv);
      idxWs[row * KNB + r3] = id3;
    }

    csum += __shfl_xor(csum, 1);
    csum += __shfl_xor(csum, 2);
    csum += __shfl_xor(csum, 4);
    csum += __shfl_xor(csum, 8);
    csum += __shfl_xor(csum, 16);
    csum += __shfl_xor(csum, 32);
    if (lane == 0) kappaWs[row] = csum * (1.0f / 16.0f);
  }
}

// ---------------------------------------------------------------------------
// Kernel 2 (verbatim r6/r8/r9, proven): per (b,i) gather 16 neighbor kappas
// for both datasets, ddof=1 std, d = std_ori - std_adv + 1e-6, reduce d^2;
// last block finalizes out = mean_b sqrt(sum_b) via device-scope atomics.
// ---------------------------------------------------------------------------
__global__ __launch_bounds__(256)
void std_dist_kernel(const float* __restrict__ kappaWs,
                     const int* __restrict__ idxWs,
                     float* __restrict__ accum,
                     float* __restrict__ out) {
  const int i = blockIdx.x * 256 + threadIdx.x;
  const int b = blockIdx.y;

  float s[2];
#pragma unroll
  for (int ds = 0; ds < 2; ++ds) {
    const size_t kb = (size_t)(ds * BATCH + b) * NPTS;
    const int4* __restrict__ ip = (const int4*)(idxWs + (kb + i) * KNB);
    const int4 q0 = ip[0], q1 = ip[1], q2 = ip[2], q3 = ip[3];
    const float* __restrict__ kp = kappaWs + kb;
    float kv[16];
    kv[0] = kp[q0.x];  kv[1] = kp[q0.y];  kv[2] = kp[q0.z];  kv[3] = kp[q0.w];
    kv[4] = kp[q1.x];  kv[5] = kp[q1.y];  kv[6] = kp[q1.z];  kv[7] = kp[q1.w];
    kv[8] = kp[q2.x];  kv[9] = kp[q2.y];  kv[10] = kp[q2.z]; kv[11] = kp[q2.w];
    kv[12] = kp[q3.x]; kv[13] = kp[q3.y]; kv[14] = kp[q3.z]; kv[15] = kp[q3.w];
    float sum = 0.f;
#pragma unroll
    for (int u = 0; u < 16; ++u) sum += kv[u];
    const float mean = sum * (1.0f / 16.0f);
    float ss = 0.f;
#pragma unroll
    for (int u = 0; u < 16; ++u) {
      const float dv = kv[u] - mean;
      ss = fmaf(dv, dv, ss);
    }
    s[ds] = sqrtf(ss * (1.0f / 15.0f));   // unbiased (ddof=1)
  }

  float dq = s[0] - s[1] + 1e-6f;          // PairwiseDistance eps inside norm
  dq = dq * dq;

  dq += __shfl_xor(dq, 32);
  dq += __shfl_xor(dq, 16);
  dq += __shfl_xor(dq, 8);
  dq += __shfl_xor(dq, 4);
  dq += __shfl_xor(dq, 2);
  dq += __shfl_xor(dq, 1);
  __shared__ float red[4];
  if ((threadIdx.x & 63) == 0) red[threadIdx.x >> 6] = dq;
  __syncthreads();

  if (threadIdx.x == 0) {
    const float blockSum = red[0] + red[1] + red[2] + red[3];
    atomicAdd(&accum[b], blockSum);
    __threadfence();
    const unsigned old = atomicAdd((unsigned int*)(accum + 4), 1u);
    if (old == 63) {                        // last of 64 blocks
      float ssum = 0.f;
#pragma unroll
      for (int bb = 0; bb < 4; ++bb) ssum += sqrtf(atomicAdd(&accum[bb], 0.0f));
      out[0] = ssum * 0.25f;
    }
  }
}

extern "C" void kernel_launch(void* const* d_in, const int* in_sizes, int n_in,
                              void* d_out, int out_size, void* d_ws, size_t ws_size,
                              hipStream_t stream) {
  const float* ori = (const float*)d_in[0];
  const float* adv = (const float*)d_in[1];
  const float* nrm = (const float*)d_in[2];
  float* out = (float*)d_out;

  float* kappaWs = (float*)d_ws;                                  // 2*4*4096 f32
  int*   idxWs   = (int*)((char*)d_ws + (size_t)2 * BATCH * NPTS * 4);
  float* accum   = (float*)((char*)d_ws + (size_t)2 * BATCH * NPTS * 4
                                        + (size_t)2 * BATCH * NPTS * KNB * 4);

  dim3 g1(NPTS / QB, BATCH, 2);
  knn_kappa_kernel<<<g1, 256, 0, stream>>>(ori, adv, nrm, kappaWs, idxWs, accum);

  dim3 g2(NPTS / 256, BATCH);
  std_dist_kernel<<<g2, 256, 0, stream>>>(kappaWs, idxWs, accum, out);
}